// Round 3
// baseline (642.278 us; speedup 1.0000x reference)
//
#include <hip/hip_runtime.h>
#include <hip/hip_bf16.h>

#define NEGINF -1e30f

__device__ __forceinline__ float fast_tanh(float x) {
    float e = __expf(fminf(2.f * x, 80.f));
    return (e - 1.f) * __builtin_amdgcn_rcpf(e + 1.f);
}
__device__ __forceinline__ float fast_sigmoid(float x) {
    return __builtin_amdgcn_rcpf(1.f + __expf(fminf(-x, 80.f)));
}

// LDS-only workgroup barrier: waits lgkmcnt(0) but leaves vmcnt untouched, so
// in-flight global loads (same-thread register destinations) and fire-and-forget
// stores are NOT drained. Safe when all cross-thread traffic goes through LDS.
__device__ __forceinline__ void bar_lds() {
    asm volatile("s_waitcnt lgkmcnt(0)\n\ts_barrier" ::: "memory");
}

// ---------------- Tiled f32 GEMM: out[M,N] = A[M,K] @ W[N,K]^T + bias ----------------
// Two weight/bias/out sets selectable by block tile (merges independent GEMMs sharing A).
// mode 0: plain bias. mode 1: out = sigmoid(acc+bias) * A[m, n]  (requires K == N)
__global__ __launch_bounds__(256) void gemm_bias(
    const float* __restrict__ A,
    const float* __restrict__ W1, const float* __restrict__ b1, float* __restrict__ out1,
    const float* __restrict__ W2, const float* __restrict__ b2, float* __restrict__ out2,
    int M, int N, int K, int nsplit, int mode) {
    __shared__ __align__(16) float At[16][64];
    __shared__ __align__(16) float Wt[16][64];
    const int tid = threadIdx.x;
    int bx = blockIdx.x;
    const float* W = W1; const float* bias = b1; float* out = out1;
    int n0;
    if (bx < nsplit) {
        n0 = bx * 64;
    } else {
        W = W2; bias = b2; out = out2;
        n0 = (bx - nsplit) * 64;
    }
    const int m0 = blockIdx.y * 64;
    const int tx = tid & 15;   // col group (4 cols)
    const int ty = tid >> 4;   // row group (4 rows)
    float acc[4][4];
#pragma unroll
    for (int r = 0; r < 4; r++)
#pragma unroll
        for (int c = 0; c < 4; c++) acc[r][c] = 0.f;

    const int lr = tid >> 2;          // 0..63 row within tile for loads
    const int lc = (tid & 3) * 4;     // 0..12 k within tile for loads

    for (int k0 = 0; k0 < K; k0 += 16) {
        float4 a = *(const float4*)(A + (size_t)(m0 + lr) * K + k0 + lc);
        float4 w = *(const float4*)(W + (size_t)(n0 + lr) * K + k0 + lc);
        At[lc + 0][lr] = a.x; At[lc + 1][lr] = a.y; At[lc + 2][lr] = a.z; At[lc + 3][lr] = a.w;
        Wt[lc + 0][lr] = w.x; Wt[lc + 1][lr] = w.y; Wt[lc + 2][lr] = w.z; Wt[lc + 3][lr] = w.w;
        __syncthreads();
#pragma unroll
        for (int kk = 0; kk < 16; kk++) {
            float4 av = *(const float4*)&At[kk][ty * 4];
            float4 wv = *(const float4*)&Wt[kk][tx * 4];
            const float* ap = (const float*)&av;
            const float* wp = (const float*)&wv;
#pragma unroll
            for (int r = 0; r < 4; r++)
#pragma unroll
                for (int c = 0; c < 4; c++) acc[r][c] += ap[r] * wp[c];
        }
        __syncthreads();
    }
    float4 bb = *(const float4*)(bias + n0 + tx * 4);
    const float* bp = (const float*)&bb;
#pragma unroll
    for (int r = 0; r < 4; r++) {
        int m = m0 + ty * 4 + r;
        float4 o;
        float* op = (float*)&o;
#pragma unroll
        for (int c = 0; c < 4; c++) op[c] = acc[r][c] + bp[c];
        if (mode == 1) {
            float4 av = *(const float4*)(A + (size_t)m * K + n0 + tx * 4);
            const float* ap = (const float*)&av;
#pragma unroll
            for (int c = 0; c < 4; c++) op[c] = fast_sigmoid(op[c]) * ap[c];
        }
        *(float4*)(out + (size_t)m * N + n0 + tx * 4) = o;
    }
}

// ---------------- Attention: scores(tanh-dot) -> masked softmax -> C = attn @ v ------
// Writes inp[b,q,:] = concat(v[b,q,:], C[b,q,:])   (inp is [B*L, 512])
__global__ __launch_bounds__(256) void attn_kernel(
    const float* __restrict__ v, const int* __restrict__ lengths,
    const float* __restrict__ own, const float* __restrict__ comp,
    const float* __restrict__ v_attn, float* __restrict__ inp) {
    const int L = 512, D = 256, H = 128;
    const int b = blockIdx.x >> 9;
    const int q = blockIdx.x & 511;
    const int tid = threadIdx.x;
    __shared__ float ownq[128];
    __shared__ float va[128];
    __shared__ float sc[512];
    __shared__ float red[256];
    if (tid < 128) {
        ownq[tid] = own[((size_t)(b * L + q)) * H + tid];
        va[tid] = v_attn[tid];
    }
    __syncthreads();
    const int len = lengths[b];
    float s2[2];
    float smax = NEGINF;
#pragma unroll
    for (int slot = 0; slot < 2; slot++) {
        int k = tid + slot * 256;
        float s = NEGINF;
        if (k < len) {
            const float* cp = comp + ((size_t)(b * L + k)) * H;
            s = 0.f;
#pragma unroll 4
            for (int h = 0; h < H; h += 4) {
                float4 c4 = *(const float4*)(cp + h);
                s += fast_tanh(ownq[h + 0] + c4.x) * va[h + 0];
                s += fast_tanh(ownq[h + 1] + c4.y) * va[h + 1];
                s += fast_tanh(ownq[h + 2] + c4.z) * va[h + 2];
                s += fast_tanh(ownq[h + 3] + c4.w) * va[h + 3];
            }
        }
        s2[slot] = s;
        smax = fmaxf(smax, s);
    }
    red[tid] = smax;
    __syncthreads();
    for (int off = 128; off > 0; off >>= 1) {
        if (tid < off) red[tid] = fmaxf(red[tid], red[tid + off]);
        __syncthreads();
    }
    float mx = red[0];
    __syncthreads();
    float lsum = 0.f;
#pragma unroll
    for (int slot = 0; slot < 2; slot++) {
        float e = __expf(s2[slot] - mx);
        sc[tid + slot * 256] = e;
        lsum += e;
    }
    red[tid] = lsum;
    __syncthreads();
    for (int off = 128; off > 0; off >>= 1) {
        if (tid < off) red[tid] += red[tid + off];
        __syncthreads();
    }
    float inv = __builtin_amdgcn_rcpf(red[0]);
    // context: thread tid owns output dim d = tid
    float a0 = 0.f, a1 = 0.f, a2 = 0.f, a3 = 0.f;
    const float* vb = v + ((size_t)b * L) * D + tid;
#pragma unroll 4
    for (int k = 0; k < L; k += 4) {
        a0 += sc[k + 0] * vb[(size_t)(k + 0) * D];
        a1 += sc[k + 1] * vb[(size_t)(k + 1) * D];
        a2 += sc[k + 2] * vb[(size_t)(k + 2) * D];
        a3 += sc[k + 3] * vb[(size_t)(k + 3) * D];
    }
    float accum = ((a0 + a1) + (a2 + a3)) * inv;
    size_t row = ((size_t)(b * L + q)) * 512;
    inp[row + 256 + tid] = accum;
    inp[row + tid] = v[((size_t)(b * L + q)) * D + tid];
}

// ---------------- Bidirectional GRU recurrence ----------------
// One block per (dir, batch). 768 threads: pair (j = tid>>1, half = tid&1) computes
// half of hp[j] = b_hh[j] + h . w_hh[j,:]; halves combined via LDS (hp0/hp1).
// Step-loop barriers are LDS-only (bar_lds): global xp loads (prefetched one step
// ahead) and out stores stay in flight across barriers — no vmcnt(0) drain per step.
__global__ __launch_bounds__(768, 3) void gru_kernel(
    const float* __restrict__ xp_f, const float* __restrict__ xp_b,
    const float* __restrict__ w_hh_f, const float* __restrict__ w_hh_b,
    const float* __restrict__ b_hh_f, const float* __restrict__ b_hh_b,
    const int* __restrict__ lengths, float* __restrict__ out) {
    const int L = 512, H = 128;
    const int dir = blockIdx.x >> 2;
    const int b = blockIdx.x & 3;
    const float* xp = dir ? xp_b : xp_f;
    const float* w_hh = dir ? w_hh_b : w_hh_f;
    const float* b_hh = dir ? b_hh_b : b_hh_f;
    const int tid = threadIdx.x;
    const int j = tid >> 1;
    const int half = tid & 1;
    __shared__ float h[128];
    __shared__ float hp0[384];
    __shared__ float hp1[384];
    // weights for this thread's half-row, in registers (16 float4 = 64 VGPR)
    float4 wr[16];
    const float4* wrow = (const float4*)(w_hh + (size_t)j * H + half * 64);
#pragma unroll
    for (int i = 0; i < 16; i++) wr[i] = wrow[i];
    const float bj = (half == 0) ? b_hh[j] : 0.f;

    const int len = lengths[b];
    // pre-zero masked tail: out[b, t, dir*128 + jj] = 0 for t in [len, L)
    for (int idx = tid; idx < (L - len) * 128; idx += 768) {
        int tt = len + (idx >> 7);
        int jj = idx & 127;
        out[((size_t)(b * L + tt)) * 256 + dir * 128 + jj] = 0.f;
    }
    if (tid < 128) h[tid] = 0.f;
    float hcur = 0.f;   // gate thread's own h[tid]
    __syncthreads();    // one full barrier before the loop is fine

    // preload xp for step 0 (gate threads only)
    float xr = 0.f, xz = 0.f, xn = 0.f;
    if (tid < 128) {
        int t0 = dir ? (len - 1) : 0;
        size_t base = ((size_t)(b * L + t0)) * 384;
        xr = xp[base + tid];
        xz = xp[base + 128 + tid];
        xn = xp[base + 256 + tid];
    }

    const float4* h4 = ((const float4*)h) + half * 16;
    for (int stp = 0; stp < len; stp++) {
        const int t = dir ? (len - 1 - stp) : stp;
        // issue prefetch for step stp+1; drains during this whole step
        float nxr = 0.f, nxz = 0.f, nxn = 0.f;
        if (tid < 128 && (stp + 1 < len)) {
            int tn = dir ? (len - 2 - stp) : (stp + 1);
            size_t base = ((size_t)(b * L + tn)) * 384;
            nxr = xp[base + tid];
            nxz = xp[base + 128 + tid];
            nxn = xp[base + 256 + tid];
        }
        // half-dot: 8 independent accumulator chains (8 serial FMAs each)
        float a0 = 0.f, a1 = 0.f, a2 = 0.f, a3 = 0.f;
        float a4 = 0.f, a5 = 0.f, a6 = 0.f, a7 = 0.f;
#pragma unroll
        for (int i = 0; i < 16; i += 2) {
            float4 h0 = h4[i];
            float4 h1 = h4[i + 1];
            a0 += h0.x * wr[i].x; a1 += h0.y * wr[i].y;
            a2 += h0.z * wr[i].z; a3 += h0.w * wr[i].w;
            a4 += h1.x * wr[i + 1].x; a5 += h1.y * wr[i + 1].y;
            a6 += h1.z * wr[i + 1].z; a7 += h1.w * wr[i + 1].w;
        }
        float s = (((a0 + a4) + (a1 + a5)) + ((a2 + a6) + (a3 + a7))) + bj;
        if (half == 0) hp0[j] = s; else hp1[j] = s;
        bar_lds();   // hp ready; all reads of h done (LDS-only wait)
        float hn;
        if (tid < 128) {
            float hr = hp0[tid] + hp1[tid];
            float hz = hp0[128 + tid] + hp1[128 + tid];
            float hh = hp0[256 + tid] + hp1[256 + tid];
            float r = fast_sigmoid(xr + hr);
            float z = fast_sigmoid(xz + hz);
            float n = fast_tanh(xn + r * hh);
            hn = (1.f - z) * n + z * hcur;
            hcur = hn;
            h[tid] = hn;
        }
        bar_lds();   // h ready (LDS-only wait)
        if (tid < 128) {
            // fire-and-forget; never drained inside the loop
            out[((size_t)(b * L + t)) * 256 + dir * 128 + tid] = hn;
            xr = nxr; xz = nxz; xn = nxn;
        }
    }
}

extern "C" void kernel_launch(void* const* d_in, const int* in_sizes, int n_in,
                              void* d_out, int out_size, void* d_ws, size_t ws_size,
                              hipStream_t stream) {
    const int B = 4, L = 512, D = 256, H = 128;
    const int M = B * L;  // 2048

    const float* v      = (const float*)d_in[0];
    const int* lengths  = (const int*)d_in[1];
    // d_in[2] = p_mask (bool) — unused, lengths is equivalent
    const float* own_W  = (const float*)d_in[3];
    const float* own_b  = (const float*)d_in[4];
    const float* comp_W = (const float*)d_in[5];
    const float* comp_b = (const float*)d_in[6];
    const float* v_attn = (const float*)d_in[7];
    const float* gate_W = (const float*)d_in[8];
    const float* gate_b = (const float*)d_in[9];
    const float* w_ih_f = (const float*)d_in[10];
    const float* w_hh_f = (const float*)d_in[11];
    const float* b_ih_f = (const float*)d_in[12];
    const float* b_hh_f = (const float*)d_in[13];
    const float* w_ih_b = (const float*)d_in[14];
    const float* w_hh_b = (const float*)d_in[15];
    const float* b_ih_b = (const float*)d_in[16];
    const float* b_hh_b = (const float*)d_in[17];

    float* ws   = (float*)d_ws;
    float* own  = ws;                       // [2048,128]
    float* comp = own + (size_t)M * H;      // [2048,128]
    float* inp  = comp + (size_t)M * H;     // [2048,512]
    float* gated = inp + (size_t)M * 512;   // [2048,512]
    float* xp_f = gated + (size_t)M * 512;  // [2048,384]
    float* xp_b = xp_f + (size_t)M * 384;   // [2048,384]
    float* out  = (float*)d_out;            // [2048,256]

    // 1: own & comp projections in one launch (tiles 0..1 -> own, 2..3 -> comp)
    gemm_bias<<<dim3(4, M / 64), 256, 0, stream>>>(
        v, own_W, own_b, own, comp_W, comp_b, comp, M, H, D, 2, 0);
    // 2: attention -> inp = [v, C]
    attn_kernel<<<dim3(B * L), 256, 0, stream>>>(v, lengths, own, comp, v_attn, inp);
    // 3: gate
    gemm_bias<<<dim3(8, M / 64), 256, 0, stream>>>(
        inp, gate_W, gate_b, gated, gate_W, gate_b, gated, M, 512, 512, 8, 1);
    // 4: input projections for both GRU directions in one launch
    gemm_bias<<<dim3(12, M / 64), 256, 0, stream>>>(
        gated, w_ih_f, b_ih_f, xp_f, w_ih_b, b_ih_b, xp_b, M, 384, 512, 6, 0);
    // 5: sequential GRU, one block per (dir, batch)
    gru_kernel<<<dim3(8), 768, 0, stream>>>(xp_f, xp_b, w_hh_f, w_hh_b, b_hh_f, b_hh_b, lengths, out);
}

// Round 4
// 637.525 us; speedup vs baseline: 1.0075x; 1.0075x over previous
//
#include <hip/hip_runtime.h>
#include <hip/hip_bf16.h>

#define NEGINF -1e30f

typedef __attribute__((ext_vector_type(8))) short short8;
typedef __attribute__((ext_vector_type(4))) float f32x4;

__device__ __forceinline__ float fast_tanh(float x) {
    float e = __expf(fminf(2.f * x, 80.f));
    return (e - 1.f) * __builtin_amdgcn_rcpf(e + 1.f);
}
__device__ __forceinline__ float fast_sigmoid(float x) {
    return __builtin_amdgcn_rcpf(1.f + __expf(fminf(-x, 80.f)));
}
// round-to-nearest-even f32 -> bf16 bits
__device__ __forceinline__ short f2bf(float f) {
    unsigned u = __float_as_uint(f);
    return (short)((u + 0x7fff + ((u >> 16) & 1)) >> 16);
}
__device__ __forceinline__ float bf2f(short b) {
    return __uint_as_float(((unsigned)(unsigned short)b) << 16);
}

// LDS-only workgroup barrier: waits lgkmcnt(0) but leaves vmcnt untouched.
__device__ __forceinline__ void bar_lds() {
    asm volatile("s_waitcnt lgkmcnt(0)\n\ts_barrier" ::: "memory");
}

// ---------------- Tiled f32 GEMM: out[M,N] = A[M,K] @ W[N,K]^T + bias ----------------
// Two weight/bias/out sets selectable by block tile (merges independent GEMMs sharing A).
// mode 0: plain bias. mode 1: out = sigmoid(acc+bias) * A[m, n]  (requires K == N)
__global__ __launch_bounds__(256) void gemm_bias(
    const float* __restrict__ A,
    const float* __restrict__ W1, const float* __restrict__ b1, float* __restrict__ out1,
    const float* __restrict__ W2, const float* __restrict__ b2, float* __restrict__ out2,
    int M, int N, int K, int nsplit, int mode) {
    __shared__ __align__(16) float At[16][64];
    __shared__ __align__(16) float Wt[16][64];
    const int tid = threadIdx.x;
    int bx = blockIdx.x;
    const float* W = W1; const float* bias = b1; float* out = out1;
    int n0;
    if (bx < nsplit) {
        n0 = bx * 64;
    } else {
        W = W2; bias = b2; out = out2;
        n0 = (bx - nsplit) * 64;
    }
    const int m0 = blockIdx.y * 64;
    const int tx = tid & 15;   // col group (4 cols)
    const int ty = tid >> 4;   // row group (4 rows)
    float acc[4][4];
#pragma unroll
    for (int r = 0; r < 4; r++)
#pragma unroll
        for (int c = 0; c < 4; c++) acc[r][c] = 0.f;

    const int lr = tid >> 2;          // 0..63 row within tile for loads
    const int lc = (tid & 3) * 4;     // 0..12 k within tile for loads

    for (int k0 = 0; k0 < K; k0 += 16) {
        float4 a = *(const float4*)(A + (size_t)(m0 + lr) * K + k0 + lc);
        float4 w = *(const float4*)(W + (size_t)(n0 + lr) * K + k0 + lc);
        At[lc + 0][lr] = a.x; At[lc + 1][lr] = a.y; At[lc + 2][lr] = a.z; At[lc + 3][lr] = a.w;
        Wt[lc + 0][lr] = w.x; Wt[lc + 1][lr] = w.y; Wt[lc + 2][lr] = w.z; Wt[lc + 3][lr] = w.w;
        __syncthreads();
#pragma unroll
        for (int kk = 0; kk < 16; kk++) {
            float4 av = *(const float4*)&At[kk][ty * 4];
            float4 wv = *(const float4*)&Wt[kk][tx * 4];
            const float* ap = (const float*)&av;
            const float* wp = (const float*)&wv;
#pragma unroll
            for (int r = 0; r < 4; r++)
#pragma unroll
                for (int c = 0; c < 4; c++) acc[r][c] += ap[r] * wp[c];
        }
        __syncthreads();
    }
    float4 bb = *(const float4*)(bias + n0 + tx * 4);
    const float* bp = (const float*)&bb;
#pragma unroll
    for (int r = 0; r < 4; r++) {
        int m = m0 + ty * 4 + r;
        float4 o;
        float* op = (float*)&o;
#pragma unroll
        for (int c = 0; c < 4; c++) op[c] = acc[r][c] + bp[c];
        if (mode == 1) {
            float4 av = *(const float4*)(A + (size_t)m * K + n0 + tx * 4);
            const float* ap = (const float*)&av;
#pragma unroll
            for (int c = 0; c < 4; c++) op[c] = fast_sigmoid(op[c]) * ap[c];
        }
        *(float4*)(out + (size_t)m * N + n0 + tx * 4) = o;
    }
}

// ---------------- Attention: scores(tanh-dot) -> masked softmax -> C = attn @ v ------
// Writes inp[b,q,:] = concat(v[b,q,:], C[b,q,:])   (inp is [B*L, 512])
__global__ __launch_bounds__(256) void attn_kernel(
    const float* __restrict__ v, const int* __restrict__ lengths,
    const float* __restrict__ own, const float* __restrict__ comp,
    const float* __restrict__ v_attn, float* __restrict__ inp) {
    const int L = 512, D = 256, H = 128;
    const int b = blockIdx.x >> 9;
    const int q = blockIdx.x & 511;
    const int tid = threadIdx.x;
    __shared__ float ownq[128];
    __shared__ float va[128];
    __shared__ float sc[512];
    __shared__ float red[256];
    if (tid < 128) {
        ownq[tid] = own[((size_t)(b * L + q)) * H + tid];
        va[tid] = v_attn[tid];
    }
    __syncthreads();
    const int len = lengths[b];
    float s2[2];
    float smax = NEGINF;
#pragma unroll
    for (int slot = 0; slot < 2; slot++) {
        int k = tid + slot * 256;
        float s = NEGINF;
        if (k < len) {
            const float* cp = comp + ((size_t)(b * L + k)) * H;
            s = 0.f;
#pragma unroll 4
            for (int h = 0; h < H; h += 4) {
                float4 c4 = *(const float4*)(cp + h);
                s += fast_tanh(ownq[h + 0] + c4.x) * va[h + 0];
                s += fast_tanh(ownq[h + 1] + c4.y) * va[h + 1];
                s += fast_tanh(ownq[h + 2] + c4.z) * va[h + 2];
                s += fast_tanh(ownq[h + 3] + c4.w) * va[h + 3];
            }
        }
        s2[slot] = s;
        smax = fmaxf(smax, s);
    }
    red[tid] = smax;
    __syncthreads();
    for (int off = 128; off > 0; off >>= 1) {
        if (tid < off) red[tid] = fmaxf(red[tid], red[tid + off]);
        __syncthreads();
    }
    float mx = red[0];
    __syncthreads();
    float lsum = 0.f;
#pragma unroll
    for (int slot = 0; slot < 2; slot++) {
        float e = __expf(s2[slot] - mx);
        sc[tid + slot * 256] = e;
        lsum += e;
    }
    red[tid] = lsum;
    __syncthreads();
    for (int off = 128; off > 0; off >>= 1) {
        if (tid < off) red[tid] += red[tid + off];
        __syncthreads();
    }
    float inv = __builtin_amdgcn_rcpf(red[0]);
    // context: thread tid owns output dim d = tid
    float a0 = 0.f, a1 = 0.f, a2 = 0.f, a3 = 0.f;
    const float* vb = v + ((size_t)b * L) * D + tid;
#pragma unroll 4
    for (int k = 0; k < L; k += 4) {
        a0 += sc[k + 0] * vb[(size_t)(k + 0) * D];
        a1 += sc[k + 1] * vb[(size_t)(k + 1) * D];
        a2 += sc[k + 2] * vb[(size_t)(k + 2) * D];
        a3 += sc[k + 3] * vb[(size_t)(k + 3) * D];
    }
    float accum = ((a0 + a1) + (a2 + a3)) * inv;
    size_t row = ((size_t)(b * L + q)) * 512;
    inp[row + 256 + tid] = accum;
    inp[row + tid] = v[((size_t)(b * L + q)) * D + tid];
}

// ---------------- Bidirectional GRU recurrence (MFMA matvec) ----------------
// One block per (dir, batch), 768 threads = 12 waves. Per step:
//   hp[384] = W_hh @ h  via mfma_f32_16x16x32_bf16, wave w owns M-tiles {2w, 2w+1}.
//   W_hh held in registers as hi/lo bf16 A-fragments (loaded once). h kept f32 in the
//   recurrence; split hi/lo bf16 into LDS each step. 3 combos (Whi*hhi + Whi*hlo +
//   Wlo*hhi) give ~2^-18 matvec error. Only C column 0 (lane&15==0) is used; all
//   lanes load identical quad-indexed B data so the result is independent of the
//   B n-mapping, and A/B share the same (quad,j)->k indexing so it cancels.
__global__ __launch_bounds__(768, 3) void gru_kernel(
    const float* __restrict__ xp_f, const float* __restrict__ xp_b,
    const float* __restrict__ w_hh_f, const float* __restrict__ w_hh_b,
    const float* __restrict__ b_hh_f, const float* __restrict__ b_hh_b,
    const int* __restrict__ lengths, float* __restrict__ out) {
    const int L = 512, H = 128;
    const int dir = blockIdx.x >> 2;
    const int b = blockIdx.x & 3;
    const float* xp = dir ? xp_b : xp_f;
    const float* w_hh = dir ? w_hh_b : w_hh_f;
    const float* b_hh = dir ? b_hh_b : b_hh_f;
    const int tid = threadIdx.x;
    const int wave = tid >> 6;
    const int lane = tid & 63;
    const int mrow = lane & 15;  // m within 16-row tile (also C column index)
    const int quad = lane >> 4;  // k-quad

    __shared__ __align__(16) short hbuf[256];  // [0,128): h_hi bf16, [128,256): h_lo bf16
    __shared__ __align__(16) float hp[384];

    // ---- A-fragments: wave w owns rows 32w..32w+31 (tiles 2w, 2w+1) ----
    short8 whi[2][4], wlo[2][4];
#pragma unroll
    for (int mt = 0; mt < 2; mt++) {
        int row = 32 * wave + 16 * mt + mrow;
#pragma unroll
        for (int kt = 0; kt < 4; kt++) {
            const float* wp = w_hh + (size_t)row * H + kt * 32 + quad * 8;
            float4 w0 = *(const float4*)(wp);
            float4 w1 = *(const float4*)(wp + 4);
            float wv[8] = {w0.x, w0.y, w0.z, w0.w, w1.x, w1.y, w1.z, w1.w};
            short8 hi8, lo8;
#pragma unroll
            for (int jj = 0; jj < 8; jj++) {
                short hb = f2bf(wv[jj]);
                hi8[jj] = hb;
                lo8[jj] = f2bf(wv[jj] - bf2f(hb));
            }
            whi[mt][kt] = hi8;
            wlo[mt][kt] = lo8;
        }
    }
    // gate-thread biases
    float br = 0.f, bz = 0.f, bn = 0.f;
    if (tid < 128) {
        br = b_hh[tid];
        bz = b_hh[128 + tid];
        bn = b_hh[256 + tid];
    }

    const int len = lengths[b];
    // pre-zero masked tail
    for (int idx = tid; idx < (L - len) * 128; idx += 768) {
        int tt = len + (idx >> 7);
        int jj = idx & 127;
        out[((size_t)(b * L + tt)) * 256 + dir * 128 + jj] = 0.f;
    }
    if (tid < 256) hbuf[tid] = 0;
    float hcur = 0.f;
    __syncthreads();

    // preload xp for step 0 (gate threads)
    float xr = 0.f, xz = 0.f, xn = 0.f;
    if (tid < 128) {
        int t0 = dir ? (len - 1) : 0;
        size_t base = ((size_t)(b * L + t0)) * 384;
        xr = xp[base + tid];
        xz = xp[base + 128 + tid];
        xn = xp[base + 256 + tid];
    }

    for (int stp = 0; stp < len; stp++) {
        const int t = dir ? (len - 1 - stp) : stp;
        // prefetch next step's xp; stays in flight across bar_lds
        float nxr = 0.f, nxz = 0.f, nxn = 0.f;
        if (tid < 128 && (stp + 1 < len)) {
            int tn = dir ? (len - 2 - stp) : (stp + 1);
            size_t base = ((size_t)(b * L + tn)) * 384;
            nxr = xp[base + tid];
            nxz = xp[base + 128 + tid];
            nxn = xp[base + 256 + tid];
        }
        // B-fragments (all lanes read quad-indexed h segment -> 4-addr broadcast)
        short8 bhi[4], blo[4];
#pragma unroll
        for (int kt = 0; kt < 4; kt++) {
            bhi[kt] = *(const short8*)&hbuf[kt * 32 + quad * 8];
            blo[kt] = *(const short8*)&hbuf[128 + kt * 32 + quad * 8];
        }
        f32x4 acc[2][3];
#pragma unroll
        for (int mt = 0; mt < 2; mt++)
#pragma unroll
            for (int cb = 0; cb < 3; cb++) acc[mt][cb] = (f32x4){0.f, 0.f, 0.f, 0.f};
#pragma unroll
        for (int kt = 0; kt < 4; kt++) {
#pragma unroll
            for (int mt = 0; mt < 2; mt++) {
                acc[mt][0] = __builtin_amdgcn_mfma_f32_16x16x32_bf16(whi[mt][kt], bhi[kt], acc[mt][0], 0, 0, 0);
                acc[mt][1] = __builtin_amdgcn_mfma_f32_16x16x32_bf16(whi[mt][kt], blo[kt], acc[mt][1], 0, 0, 0);
                acc[mt][2] = __builtin_amdgcn_mfma_f32_16x16x32_bf16(wlo[mt][kt], bhi[kt], acc[mt][2], 0, 0, 0);
            }
        }
        if (mrow == 0) {  // C column 0: rows = quad*4 + reg
            f32x4 r0 = acc[0][0] + acc[0][1] + acc[0][2];
            f32x4 r1 = acc[1][0] + acc[1][1] + acc[1][2];
            *(f32x4*)&hp[32 * wave + quad * 4] = r0;
            *(f32x4*)&hp[32 * wave + 16 + quad * 4] = r1;
        }
        bar_lds();  // hp ready; hbuf reads done
        float hn;
        if (tid < 128) {
            float hr = hp[tid] + br;
            float hz = hp[128 + tid] + bz;
            float hh = hp[256 + tid] + bn;
            float r = fast_sigmoid(xr + hr);
            float z = fast_sigmoid(xz + hz);
            float n = fast_tanh(xn + r * hh);
            hn = (1.f - z) * n + z * hcur;
            hcur = hn;
            short hb = f2bf(hn);
            hbuf[tid] = hb;
            hbuf[128 + tid] = f2bf(hn - bf2f(hb));
        }
        bar_lds();  // hbuf ready
        if (tid < 128) {
            out[((size_t)(b * L + t)) * 256 + dir * 128 + tid] = hn;  // fire-and-forget
            xr = nxr; xz = nxz; xn = nxn;
        }
    }
}

extern "C" void kernel_launch(void* const* d_in, const int* in_sizes, int n_in,
                              void* d_out, int out_size, void* d_ws, size_t ws_size,
                              hipStream_t stream) {
    const int B = 4, L = 512, D = 256, H = 128;
    const int M = B * L;  // 2048

    const float* v      = (const float*)d_in[0];
    const int* lengths  = (const int*)d_in[1];
    // d_in[2] = p_mask (bool) — unused, lengths is equivalent
    const float* own_W  = (const float*)d_in[3];
    const float* own_b  = (const float*)d_in[4];
    const float* comp_W = (const float*)d_in[5];
    const float* comp_b = (const float*)d_in[6];
    const float* v_attn = (const float*)d_in[7];
    const float* gate_W = (const float*)d_in[8];
    const float* gate_b = (const float*)d_in[9];
    const float* w_ih_f = (const float*)d_in[10];
    const float* w_hh_f = (const float*)d_in[11];
    const float* b_ih_f = (const float*)d_in[12];
    const float* b_hh_f = (const float*)d_in[13];
    const float* w_ih_b = (const float*)d_in[14];
    const float* w_hh_b = (const float*)d_in[15];
    const float* b_ih_b = (const float*)d_in[16];
    const float* b_hh_b = (const float*)d_in[17];

    float* ws   = (float*)d_ws;
    float* own  = ws;                       // [2048,128]
    float* comp = own + (size_t)M * H;      // [2048,128]
    float* inp  = comp + (size_t)M * H;     // [2048,512]
    float* gated = inp + (size_t)M * 512;   // [2048,512]
    float* xp_f = gated + (size_t)M * 512;  // [2048,384]
    float* xp_b = xp_f + (size_t)M * 384;   // [2048,384]
    float* out  = (float*)d_out;            // [2048,256]

    // 1: own & comp projections in one launch (tiles 0..1 -> own, 2..3 -> comp)
    gemm_bias<<<dim3(4, M / 64), 256, 0, stream>>>(
        v, own_W, own_b, own, comp_W, comp_b, comp, M, H, D, 2, 0);
    // 2: attention -> inp = [v, C]
    attn_kernel<<<dim3(B * L), 256, 0, stream>>>(v, lengths, own, comp, v_attn, inp);
    // 3: gate
    gemm_bias<<<dim3(8, M / 64), 256, 0, stream>>>(
        inp, gate_W, gate_b, gated, gate_W, gate_b, gated, M, 512, 512, 8, 1);
    // 4: input projections for both GRU directions in one launch
    gemm_bias<<<dim3(12, M / 64), 256, 0, stream>>>(
        gated, w_ih_f, b_ih_f, xp_f, w_ih_b, b_ih_b, xp_b, M, 384, 512, 6, 0);
    // 5: sequential GRU, one block per (dir, batch)
    gru_kernel<<<dim3(8), 768, 0, stream>>>(xp_f, xp_b, w_hh_f, w_hh_b, b_hh_f, b_hh_b, lengths, out);
}